// Round 3
// baseline (392.242 us; speedup 1.0000x reference)
//
#include <hip/hip_runtime.h>
#include <hip/hip_bf16.h>
#include <stdint.h>

#define RANK 32
#define SCALE (1.0f / 32.0f)

typedef __bf16 bf16x8 __attribute__((ext_vector_type(8)));
typedef float f32x4 __attribute__((ext_vector_type(4)));

// ---------------------------------------------------------------------------
// async global->LDS, 16B per lane
// ---------------------------------------------------------------------------
__device__ __forceinline__ void gload16(const void* g, void* l) {
  __builtin_amdgcn_global_load_lds(
      (const __attribute__((address_space(1))) unsigned int*)g,
      (__attribute__((address_space(3))) unsigned int*)l, 16, 0, 0);
}

__device__ __forceinline__ unsigned short f2bf(float f) {
  __hip_bfloat16 h = __float2bfloat16(f);
  return *reinterpret_cast<unsigned short*>(&h);
}

// ---------------------------------------------------------------------------
// Bt[o][r] = B[r][o]
// ---------------------------------------------------------------------------
__global__ __launch_bounds__(256) void transpose_B_k(const float* __restrict__ B,
                                                     float* __restrict__ Bt,
                                                     int Dout) {
  int idx = blockIdx.x * 256 + threadIdx.x;
  int r = idx / Dout;
  int o = idx - r * Dout;
  Bt[(long long)o * RANK + r] = B[idx];
}

// ---------------------------------------------------------------------------
// W'b[o][i] = bf16( W[o][i] + SCALE * dot32(A[i][:], Bt[o][:]) )
// ---------------------------------------------------------------------------
__global__ __launch_bounds__(256) void merge_W_k(const float* __restrict__ W,
                                                 const float* __restrict__ A,
                                                 const float* __restrict__ Bt,
                                                 unsigned short* __restrict__ Wb,
                                                 int Din, int Dout) {
  __shared__ float sB[16 * RANK];
  int nib = Din / 256;
  int ib = blockIdx.x % nib;
  int ob = blockIdx.x / nib;
  int i0 = ib * 256, o0 = ob * 16;
  int t = threadIdx.x;

  if (t < 128) {
    reinterpret_cast<float4*>(sB)[t] =
        reinterpret_cast<const float4*>(Bt + (long long)o0 * RANK)[t];
  }

  float a[RANK];
  const float4* Ap = reinterpret_cast<const float4*>(A + (long long)(i0 + t) * RANK);
#pragma unroll
  for (int c = 0; c < RANK / 4; ++c) {
    float4 v = Ap[c];
    a[c * 4 + 0] = v.x; a[c * 4 + 1] = v.y;
    a[c * 4 + 2] = v.z; a[c * 4 + 3] = v.w;
  }
  __syncthreads();

  for (int o = 0; o < 16; ++o) {
    float d = 0.f;
#pragma unroll
    for (int j = 0; j < RANK; ++j) d += a[j] * sB[o * RANK + j];
    long long off = (long long)(o0 + o) * Din + i0 + t;
    Wb[off] = f2bf(W[off] + SCALE * d);
  }
}

// ---------------------------------------------------------------------------
// x fp32 -> bf16, 8 elems/thread
// ---------------------------------------------------------------------------
__global__ __launch_bounds__(256) void cast_x_k(const float* __restrict__ in,
                                                unsigned short* __restrict__ out,
                                                long long n8) {
  long long i = (long long)blockIdx.x * 256 + threadIdx.x;
  if (i >= n8) return;
  const float4* in4 = reinterpret_cast<const float4*>(in) + i * 2;
  float4 v0 = in4[0], v1 = in4[1];
  union { unsigned short u[8]; uint4 q; } p;
  p.u[0] = f2bf(v0.x); p.u[1] = f2bf(v0.y); p.u[2] = f2bf(v0.z); p.u[3] = f2bf(v0.w);
  p.u[4] = f2bf(v1.x); p.u[5] = f2bf(v1.y); p.u[6] = f2bf(v1.z); p.u[7] = f2bf(v1.w);
  reinterpret_cast<uint4*>(out)[i] = p.q;
}

// ---------------------------------------------------------------------------
// 256x256 / BK=64 / 8-wave / 4-phase K-loop with FULL LDS READ-AHEAD.
//
// Fragment schedule (tile X, buffers c=X&1, c'=c^1):
//   P1: MFMA a_lo(X)*b_lo(X)            [frags read during P4(X-1)]
//       stage B(X+1) rows 0-127 -> Bs[c']
//   P2: MFMA a_lo(X)*b_hi(X); a_hi(X) reads interleaved after each a[m]'s
//       last use (WAR-anchored, +0 regs); stage B(X+1) rows 128-255
//   P3: MFMA a_hi(X)*b_hi(X)            [a_hi landed during P3's wait]
//   P4: stage A(X+2)->As[c]; vmcnt(4) [in-order: A(X+1),B(X+1) resident];
//       barrier (cross-wave visibility); read b_lo(X+1)->b0n early;
//       MFMA a_hi(X)*b_lo(X) with a_lo(X+1) reads interleaved;
//       tail: read b_hi(X+1)->b1; b0 = b0n.
// Barriers: 5/tile (P1..P4 close + P4 post-vmcnt). lgkm waits: compiler
// auto-counted (no inline lgkm asm -> no rule-18 hazard).
// ---------------------------------------------------------------------------
template <int NISSUE>
__device__ __forceinline__ void stage(const unsigned short* g, int K, int koff,
                                      int row0, unsigned short* ldsbase,
                                      int t, int wid) {
  int r = t >> 3;                    // local row within 64-row issue
  int cg = (t & 7) ^ (r & 7);        // inverse-swizzled global 16B chunk
#pragma unroll
  for (int i = 0; i < NISSUE; ++i) {
    gload16(g + (long long)(row0 + i * 64 + r) * K + koff + cg * 8,
            ldsbase + (row0 + i * 64) * 64 + wid * 512);
  }
}

__device__ __forceinline__ int swz_off(int rowl, int k) {
  // element offset of (rowl, k..k+7) under st-swizzle (16B chunk XOR row&7)
  return rowl * 64 + ((((k) >> 3) ^ (rowl & 7)) << 3);
}

__global__ __launch_bounds__(512, 2) void gemm256_bias_k(
    const unsigned short* __restrict__ Xb,   // [M][K] bf16
    const unsigned short* __restrict__ Wb,   // [N][K] bf16
    const float* __restrict__ bias,          // [N]
    float* __restrict__ Out,                 // [M][N] fp32
    int M, int N, int K) {
  __shared__ unsigned short As[2][256 * 64];
  __shared__ unsigned short Bs[2][256 * 64];

  int nbn = N / 256;
  int cpx = gridDim.x >> 3;
  int bid = blockIdx.x;
  int swz = (bid & 7) * cpx + (bid >> 3);      // XCD-aware swizzle (T1)
  int bm = swz / nbn, bn = swz % nbn;

  int t = threadIdx.x;
  int wid = t >> 6, lane = t & 63;
  int wr = wid >> 2, wc = wid & 3;             // 2x4 wave grid
  int lr = lane & 15, kq = (lane >> 4) * 8;
  int aw = wr * 128, bw = wc * 64;

  const unsigned short* ga = Xb + (long long)bm * 256 * K;
  const unsigned short* gb = Wb + (long long)bn * 256 * K;

  f32x4 acc[8][4] = {};
  bf16x8 a[4][2], b0[2][2], b0n[2][2], b1[2][2];

  const int NT = K / 64;

#define LDA(BUF, ROFF, MM, KS) \
  (*(const bf16x8*)&As[BUF][swz_off(aw + (ROFF) + (MM) * 16 + lr, (KS) * 32 + kq)])
#define LDB(BUF, ROFF, NN, KS) \
  (*(const bf16x8*)&Bs[BUF][swz_off(bw + (ROFF) + (NN) * 16 + lr, (KS) * 32 + kq)])

  // prologue: A(0),B(0) staged+drained; A(1) in flight; tile-0 frags to regs
  stage<4>(ga, K, 0, 0, &As[0][0], t, wid);
  stage<4>(gb, K, 0, 0, &Bs[0][0], t, wid);
  stage<4>(ga, K, 64, 0, &As[1][0], t, wid);
  asm volatile("s_waitcnt vmcnt(4)" ::: "memory");
  __builtin_amdgcn_s_barrier();
#pragma unroll
  for (int m = 0; m < 4; ++m) {
    a[m][0] = LDA(0, 0, m, 0); a[m][1] = LDA(0, 0, m, 1);
  }
#pragma unroll
  for (int n = 0; n < 2; ++n) {
    b0[n][0] = LDB(0, 0, n, 0);  b0[n][1] = LDB(0, 0, n, 1);
    b1[n][0] = LDB(0, 32, n, 0); b1[n][1] = LDB(0, 32, n, 1);
  }

  for (int kt = 0; kt < NT; ++kt) {
    const int cur = kt & 1;
    int konext = (kt + 1) * 64, konext2 = (kt + 2) * 64;
    const bool hasN = (kt + 1 < NT);

    // ---------- P1: MFMA a_lo*b_lo; stage B(next) rows 0-127
    if (hasN) stage<2>(gb, K, konext, 0, &Bs[cur ^ 1][0], t, wid);
    __builtin_amdgcn_s_setprio(1);
#pragma unroll
    for (int m = 0; m < 4; ++m)
#pragma unroll
      for (int n = 0; n < 2; ++n)
#pragma unroll
        for (int ks = 0; ks < 2; ++ks)
          acc[m][n] = __builtin_amdgcn_mfma_f32_16x16x32_bf16(a[m][ks], b0[n][ks], acc[m][n], 0, 0, 0);
    __builtin_amdgcn_s_setprio(0);
    __builtin_amdgcn_s_barrier();

    // ---------- P2: MFMA a_lo*b_hi with a_hi reads interleaved (WAR-anchored)
    if (hasN) stage<2>(gb, K, konext, 128, &Bs[cur ^ 1][0], t, wid);
    __builtin_amdgcn_s_setprio(1);
#pragma unroll
    for (int m = 0; m < 4; ++m) {
      acc[m][2] = __builtin_amdgcn_mfma_f32_16x16x32_bf16(a[m][0], b1[0][0], acc[m][2], 0, 0, 0);
      acc[m][2] = __builtin_amdgcn_mfma_f32_16x16x32_bf16(a[m][1], b1[0][1], acc[m][2], 0, 0, 0);
      acc[m][3] = __builtin_amdgcn_mfma_f32_16x16x32_bf16(a[m][0], b1[1][0], acc[m][3], 0, 0, 0);
      acc[m][3] = __builtin_amdgcn_mfma_f32_16x16x32_bf16(a[m][1], b1[1][1], acc[m][3], 0, 0, 0);
      a[m][0] = LDA(cur, 64, m, 0);   // a_hi(X): overwrite forces post-use issue
      a[m][1] = LDA(cur, 64, m, 1);
    }
    __builtin_amdgcn_s_setprio(0);
    __builtin_amdgcn_s_barrier();

    // ---------- P3: MFMA a_hi*b_hi (compiler-counted lgkm wait on a_hi)
    __builtin_amdgcn_s_setprio(1);
#pragma unroll
    for (int m = 0; m < 4; ++m)
#pragma unroll
      for (int n = 0; n < 2; ++n)
#pragma unroll
        for (int ks = 0; ks < 2; ++ks)
          acc[4 + m][2 + n] = __builtin_amdgcn_mfma_f32_16x16x32_bf16(a[m][ks], b1[n][ks], acc[4 + m][2 + n], 0, 0, 0);
    __builtin_amdgcn_s_setprio(0);
    __builtin_amdgcn_s_barrier();

    // ---------- P4: stage A(X+2); counted vmcnt; barrier; read-ahead X+1
    if (kt + 2 < NT) {
      stage<4>(ga, K, konext2, 0, &As[cur][0], t, wid);
      asm volatile("s_waitcnt vmcnt(4)" ::: "memory");
    } else if (hasN) {
      asm volatile("s_waitcnt vmcnt(0)" ::: "memory");
    }
    __builtin_amdgcn_s_barrier();   // all waves' staged data now visible

    if (hasN) {
      b0n[0][0] = LDB(cur ^ 1, 0, 0, 0); b0n[0][1] = LDB(cur ^ 1, 0, 0, 1);
      b0n[1][0] = LDB(cur ^ 1, 0, 1, 0); b0n[1][1] = LDB(cur ^ 1, 0, 1, 1);
    }
    __builtin_amdgcn_s_setprio(1);
#pragma unroll
    for (int m = 0; m < 4; ++m) {
      acc[4 + m][0] = __builtin_amdgcn_mfma_f32_16x16x32_bf16(a[m][0], b0[0][0], acc[4 + m][0], 0, 0, 0);
      acc[4 + m][0] = __builtin_amdgcn_mfma_f32_16x16x32_bf16(a[m][1], b0[0][1], acc[4 + m][0], 0, 0, 0);
      acc[4 + m][1] = __builtin_amdgcn_mfma_f32_16x16x32_bf16(a[m][0], b0[1][0], acc[4 + m][1], 0, 0, 0);
      acc[4 + m][1] = __builtin_amdgcn_mfma_f32_16x16x32_bf16(a[m][1], b0[1][1], acc[4 + m][1], 0, 0, 0);
      if (hasN) {
        a[m][0] = LDA(cur ^ 1, 0, m, 0);   // a_lo(X+1), WAR-anchored
        a[m][1] = LDA(cur ^ 1, 0, m, 1);
      }
    }
    __builtin_amdgcn_s_setprio(0);
    if (hasN) {
      b1[0][0] = LDB(cur ^ 1, 32, 0, 0); b1[0][1] = LDB(cur ^ 1, 32, 0, 1);
      b1[1][0] = LDB(cur ^ 1, 32, 1, 0); b1[1][1] = LDB(cur ^ 1, 32, 1, 1);
      b0[0][0] = b0n[0][0]; b0[0][1] = b0n[0][1];
      b0[1][0] = b0n[1][0]; b0[1][1] = b0n[1][1];
    }
    __builtin_amdgcn_s_barrier();
  }
#undef LDA
#undef LDB

  // epilogue: C/D layout col=lane&15, row=(lane>>4)*4+v
  long long orow = (long long)bm * 256 + wr * 128;
  int ocol = bn * 256 + wc * 64;
#pragma unroll
  for (int n = 0; n < 4; ++n) {
    int gc = ocol + n * 16 + lr;
    float bv = bias[gc];
#pragma unroll
    for (int m = 0; m < 8; ++m) {
      long long gr = orow + m * 16 + (lane >> 4) * 4;
#pragma unroll
      for (int v = 0; v < 4; ++v)
        Out[(gr + v) * N + gc] = acc[m][n][v] + bv;
    }
  }
}

// ---------------------------------------------------------------------------
extern "C" void kernel_launch(void* const* d_in, const int* in_sizes, int n_in,
                              void* d_out, int out_size, void* d_ws, size_t ws_size,
                              hipStream_t stream) {
  const float* x    = (const float*)d_in[0];
  const float* W    = (const float*)d_in[1];
  const float* bias = (const float*)d_in[2];
  const float* A    = (const float*)d_in[3];
  const float* B    = (const float*)d_in[4];

  int Din  = in_sizes[3] / RANK;                 // 4096
  int Dout = in_sizes[4] / RANK;                 // 4096
  long long M = (long long)in_sizes[0] / Din;    // 8192

  size_t xb_bytes = (size_t)M * Din * 2;
  size_t wb_bytes = (size_t)Dout * Din * 2;
  size_t bt_bytes = (size_t)Dout * RANK * 4;
  if (ws_size < xb_bytes + wb_bytes + bt_bytes) return;

  char* ws = (char*)d_ws;
  unsigned short* Xb = (unsigned short*)ws;
  unsigned short* Wb = (unsigned short*)(ws + xb_bytes);
  float* Bt          = (float*)(ws + xb_bytes + wb_bytes);

  transpose_B_k<<<dim3((Dout * RANK) / 256), dim3(256), 0, stream>>>(B, Bt, Dout);
  merge_W_k<<<dim3((Dout / 16) * (Din / 256)), dim3(256), 0, stream>>>(W, A, Bt, Wb, Din, Dout);
  long long n8 = M * Din / 8;
  cast_x_k<<<dim3((unsigned)(n8 / 256)), dim3(256), 0, stream>>>(x, Xb, n8);
  gemm256_bias_k<<<dim3((unsigned)((M / 256) * (Dout / 256))), dim3(512), 0, stream>>>(
      Xb, Wb, bias, (float*)d_out, (int)M, Dout, Din);
}

// Round 4
// 345.886 us; speedup vs baseline: 1.1340x; 1.1340x over previous
//
#include <hip/hip_runtime.h>
#include <hip/hip_bf16.h>
#include <stdint.h>

#define RANK 32
#define SCALE (1.0f / 32.0f)

typedef __bf16 bf16x8 __attribute__((ext_vector_type(8)));
typedef float f32x4 __attribute__((ext_vector_type(4)));

// ---------------------------------------------------------------------------
// async global->LDS, 16B per lane
// ---------------------------------------------------------------------------
__device__ __forceinline__ void gload16(const void* g, void* l) {
  __builtin_amdgcn_global_load_lds(
      (const __attribute__((address_space(1))) unsigned int*)g,
      (__attribute__((address_space(3))) unsigned int*)l, 16, 0, 0);
}

__device__ __forceinline__ unsigned short f2bf(float f) {
  __hip_bfloat16 h = __float2bfloat16(f);
  return *reinterpret_cast<unsigned short*>(&h);
}

// ---------------------------------------------------------------------------
// Bt[o][r] = B[r][o]
// ---------------------------------------------------------------------------
__global__ __launch_bounds__(256) void transpose_B_k(const float* __restrict__ B,
                                                     float* __restrict__ Bt,
                                                     int Dout) {
  int idx = blockIdx.x * 256 + threadIdx.x;
  int r = idx / Dout;
  int o = idx - r * Dout;
  Bt[(long long)o * RANK + r] = B[idx];
}

// ---------------------------------------------------------------------------
// W'b[o][i] = bf16( W[o][i] + SCALE * dot32(A[i][:], Bt[o][:]) )
// ---------------------------------------------------------------------------
__global__ __launch_bounds__(256) void merge_W_k(const float* __restrict__ W,
                                                 const float* __restrict__ A,
                                                 const float* __restrict__ Bt,
                                                 unsigned short* __restrict__ Wb,
                                                 int Din, int Dout) {
  __shared__ float sB[16 * RANK];
  int nib = Din / 256;
  int ib = blockIdx.x % nib;
  int ob = blockIdx.x / nib;
  int i0 = ib * 256, o0 = ob * 16;
  int t = threadIdx.x;

  if (t < 128) {
    reinterpret_cast<float4*>(sB)[t] =
        reinterpret_cast<const float4*>(Bt + (long long)o0 * RANK)[t];
  }

  float a[RANK];
  const float4* Ap = reinterpret_cast<const float4*>(A + (long long)(i0 + t) * RANK);
#pragma unroll
  for (int c = 0; c < RANK / 4; ++c) {
    float4 v = Ap[c];
    a[c * 4 + 0] = v.x; a[c * 4 + 1] = v.y;
    a[c * 4 + 2] = v.z; a[c * 4 + 3] = v.w;
  }
  __syncthreads();

  for (int o = 0; o < 16; ++o) {
    float d = 0.f;
#pragma unroll
    for (int j = 0; j < RANK; ++j) d += a[j] * sB[o * RANK + j];
    long long off = (long long)(o0 + o) * Din + i0 + t;
    Wb[off] = f2bf(W[off] + SCALE * d);
  }
}

// ---------------------------------------------------------------------------
// x fp32 -> bf16, 8 elems/thread
// ---------------------------------------------------------------------------
__global__ __launch_bounds__(256) void cast_x_k(const float* __restrict__ in,
                                                unsigned short* __restrict__ out,
                                                long long n8) {
  long long i = (long long)blockIdx.x * 256 + threadIdx.x;
  if (i >= n8) return;
  const float4* in4 = reinterpret_cast<const float4*>(in) + i * 2;
  float4 v0 = in4[0], v1 = in4[1];
  union { unsigned short u[8]; uint4 q; } p;
  p.u[0] = f2bf(v0.x); p.u[1] = f2bf(v0.y); p.u[2] = f2bf(v0.z); p.u[3] = f2bf(v0.w);
  p.u[4] = f2bf(v1.x); p.u[5] = f2bf(v1.y); p.u[6] = f2bf(v1.z); p.u[7] = f2bf(v1.w);
  reinterpret_cast<uint4*>(out)[i] = p.q;
}

// ---------------------------------------------------------------------------
// Faithful m201 geometry: 256x256 / BK=64 / 8 waves (2Mx4N) / 2 K-tiles per
// iteration / 8 phases / 1 half-tile (2 gloads) staged per phase /
// vmcnt(6) = 3 half-tiles in flight, at phases 4 and 8 only.
//
// Wave->output remap so half-tiles are 128 contiguous rows:
//   wave wr owns A rows {wr*64..+63} u {128+wr*64..+63}
//   wave wc owns B rows {wc*32..+31} u {128+wc*32..+31}
// Half-tiles: Ha1=A[0:128], Ha2=A[128:256], Hb1=B[0:128], Hb2=B[128:256].
// Per K-tile quadrants: Q1=a_lo*b_lo (needs Ha1,Hb1), Q2=a_lo*b_hi (Hb2),
// Q3=a_hi*b_hi (Ha2), Q4=a_hi*b_lo (regs only).
//
// Stage ledger (iteration j; X=2j->buf0, Y=2j+1->buf1; X'=2j+2, Y'=2j+3):
//   P1: Ha2(Y)->buf1   P2: Ha1(X')->buf0  P3: Hb1(X')->buf0  P4: Hb2(X')+vmcnt(6)
//   P5: Ha2(X')->buf0  P6: Ha1(Y')->buf1  P7: Hb1(Y')->buf1  P8: Hb2(Y')+vmcnt(6)
// Residency: P4's vmcnt(6) leaves exactly {P2,P3,P4} stages outstanding =>
// tile Y complete before P5. P8's leaves {P6,P7,P8} => X' complete before
// P1(j+1). WAR: every stage target's last ds_read is >=1 barrier earlier
// (reads drain via compiler lgkmcnt before each MFMA cluster).
// Prologue: 7 halves (tile0 full + Y=1's Ha1,Hb1,Hb2), vmcnt(6) => tile0
// complete, 3 in flight — matches template's steady state.
// ---------------------------------------------------------------------------
__device__ __forceinline__ void stage2(const unsigned short* g, int K, int koff,
                                       int row0, unsigned short* ldsreg,
                                       int t, int wid) {
  int r = t >> 3;                    // 0..63
  int cg = (t & 7) ^ (r & 7);        // inverse-swizzled global 16B chunk
  gload16(g + (long long)(row0 + r) * K + koff + cg * 8,
          ldsreg + row0 * 64 + wid * 512);
  gload16(g + (long long)(row0 + 64 + r) * K + koff + cg * 8,
          ldsreg + (row0 + 64) * 64 + wid * 512);
}

__device__ __forceinline__ int swz_off(int rowl, int k) {
  return rowl * 64 + ((((k) >> 3) ^ (rowl & 7)) << 3);
}

__global__ __launch_bounds__(512, 2) void gemm256_bias_k(
    const unsigned short* __restrict__ Xb,   // [M][K] bf16
    const unsigned short* __restrict__ Wb,   // [N][K] bf16
    const float* __restrict__ bias,          // [N]
    float* __restrict__ Out,                 // [M][N] fp32
    int M, int N, int K) {
  __shared__ unsigned short As[2][256 * 64];
  __shared__ unsigned short Bs[2][256 * 64];

  int nbn = N / 256;
  int cpx = gridDim.x >> 3;
  int bid = blockIdx.x;
  int swz = (bid & 7) * cpx + (bid >> 3);      // XCD-aware swizzle (T1)
  int bm = swz / nbn, bn = swz % nbn;

  int t = threadIdx.x;
  int wid = t >> 6, lane = t & 63;
  int wr = wid >> 2, wc = wid & 3;             // 2x4 wave grid
  int lr = lane & 15, kq = (lane >> 4) * 8;
  int wr64 = wr * 64, wc32 = wc * 32;

  const unsigned short* ga = Xb + (long long)bm * 256 * K;
  const unsigned short* gb = Wb + (long long)bn * 256 * K;

  f32x4 acc[8][4] = {};
  bf16x8 a[4][2], b0[2][2], b1[2][2];

  const int NT = K / 64;        // 64
  const int iters = NT / 2;     // 32

#define LDA(BUF, ROWBASE, KS) \
  (*(const bf16x8*)&As[BUF][swz_off((ROWBASE) + lr, (KS) * 32 + kq)])
#define LDB(BUF, ROWBASE, KS) \
  (*(const bf16x8*)&Bs[BUF][swz_off((ROWBASE) + lr, (KS) * 32 + kq)])

#define MFMA_Q(ACLUST, BCLUST, MOFF, NOFF)                                   \
  __builtin_amdgcn_s_setprio(1);                                             \
  _Pragma("unroll")                                                          \
  for (int m = 0; m < 4; ++m)                                                \
    _Pragma("unroll")                                                        \
    for (int n = 0; n < 2; ++n)                                              \
      _Pragma("unroll")                                                      \
      for (int ks = 0; ks < 2; ++ks)                                         \
        acc[(MOFF) + m][(NOFF) + n] = __builtin_amdgcn_mfma_f32_16x16x32_bf16(\
            ACLUST[m][ks], BCLUST[n][ks], acc[(MOFF) + m][(NOFF) + n], 0, 0, 0); \
  __builtin_amdgcn_s_setprio(0);

  // ---- prologue: tile0 (buf0) full + tile1 (buf1) Ha1,Hb1,Hb2; vmcnt(6)
  stage2(ga, K, 0, 0, &As[0][0], t, wid);     // Ha1(0)
  stage2(gb, K, 0, 0, &Bs[0][0], t, wid);     // Hb1(0)
  stage2(gb, K, 0, 128, &Bs[0][0], t, wid);   // Hb2(0)
  stage2(ga, K, 0, 128, &As[0][0], t, wid);   // Ha2(0)
  stage2(ga, K, 64, 0, &As[1][0], t, wid);    // Ha1(1)
  stage2(gb, K, 64, 0, &Bs[1][0], t, wid);    // Hb1(1)
  stage2(gb, K, 64, 128, &Bs[1][0], t, wid);  // Hb2(1)
  asm volatile("s_waitcnt vmcnt(6)" ::: "memory");
  __builtin_amdgcn_s_barrier();

  for (int j = 0; j < iters; ++j) {
    const bool more = (j + 1 < iters);
    int koY = (2 * j + 1) * 64, koX2 = koY + 64, koY2 = koX2 + 64;

    // ---------- P1 (tile X=2j, Q1): read a_lo,b_lo; stage Ha2(Y)->buf1
#pragma unroll
    for (int m = 0; m < 4; ++m) {
      a[m][0] = LDA(0, wr64 + m * 16, 0); a[m][1] = LDA(0, wr64 + m * 16, 1);
    }
#pragma unroll
    for (int n = 0; n < 2; ++n) {
      b0[n][0] = LDB(0, wc32 + n * 16, 0); b0[n][1] = LDB(0, wc32 + n * 16, 1);
    }
    stage2(ga, K, koY, 128, &As[1][0], t, wid);
    __builtin_amdgcn_s_barrier();
    MFMA_Q(a, b0, 0, 0)
    __builtin_amdgcn_s_barrier();

    // ---------- P2 (Q2): read b_hi; stage Ha1(X')->buf0
#pragma unroll
    for (int n = 0; n < 2; ++n) {
      b1[n][0] = LDB(0, 128 + wc32 + n * 16, 0); b1[n][1] = LDB(0, 128 + wc32 + n * 16, 1);
    }
    if (more) stage2(ga, K, koX2, 0, &As[0][0], t, wid);
    __builtin_amdgcn_s_barrier();
    MFMA_Q(a, b1, 0, 2)
    __builtin_amdgcn_s_barrier();

    // ---------- P3 (Q3): read a_hi; stage Hb1(X')->buf0
#pragma unroll
    for (int m = 0; m < 4; ++m) {
      a[m][0] = LDA(0, 128 + wr64 + m * 16, 0); a[m][1] = LDA(0, 128 + wr64 + m * 16, 1);
    }
    if (more) stage2(gb, K, koX2, 0, &Bs[0][0], t, wid);
    __builtin_amdgcn_s_barrier();
    MFMA_Q(a, b1, 4, 2)
    __builtin_amdgcn_s_barrier();

    // ---------- P4 (Q4): stage Hb2(X')->buf0; counted vmcnt
    if (more) {
      stage2(gb, K, koX2, 128, &Bs[0][0], t, wid);
      asm volatile("s_waitcnt vmcnt(6)" ::: "memory");
    } else {
      asm volatile("s_waitcnt vmcnt(0)" ::: "memory");
    }
    __builtin_amdgcn_s_barrier();
    MFMA_Q(a, b0, 4, 0)
    __builtin_amdgcn_s_barrier();

    // ---------- P5 (tile Y=2j+1, Q1): stage Ha2(X')->buf0
#pragma unroll
    for (int m = 0; m < 4; ++m) {
      a[m][0] = LDA(1, wr64 + m * 16, 0); a[m][1] = LDA(1, wr64 + m * 16, 1);
    }
#pragma unroll
    for (int n = 0; n < 2; ++n) {
      b0[n][0] = LDB(1, wc32 + n * 16, 0); b0[n][1] = LDB(1, wc32 + n * 16, 1);
    }
    if (more) stage2(ga, K, koX2, 128, &As[0][0], t, wid);
    __builtin_amdgcn_s_barrier();
    MFMA_Q(a, b0, 0, 0)
    __builtin_amdgcn_s_barrier();

    // ---------- P6 (Q2): stage Ha1(Y')->buf1
#pragma unroll
    for (int n = 0; n < 2; ++n) {
      b1[n][0] = LDB(1, 128 + wc32 + n * 16, 0); b1[n][1] = LDB(1, 128 + wc32 + n * 16, 1);
    }
    if (more) stage2(ga, K, koY2, 0, &As[1][0], t, wid);
    __builtin_amdgcn_s_barrier();
    MFMA_Q(a, b1, 0, 2)
    __builtin_amdgcn_s_barrier();

    // ---------- P7 (Q3): stage Hb1(Y')->buf1
#pragma unroll
    for (int m = 0; m < 4; ++m) {
      a[m][0] = LDA(1, 128 + wr64 + m * 16, 0); a[m][1] = LDA(1, 128 + wr64 + m * 16, 1);
    }
    if (more) stage2(gb, K, koY2, 0, &Bs[1][0], t, wid);
    __builtin_amdgcn_s_barrier();
    MFMA_Q(a, b1, 4, 2)
    __builtin_amdgcn_s_barrier();

    // ---------- P8 (Q4): stage Hb2(Y')->buf1; counted vmcnt
    if (more) {
      stage2(gb, K, koY2, 128, &Bs[1][0], t, wid);
      asm volatile("s_waitcnt vmcnt(6)" ::: "memory");
    }
    __builtin_amdgcn_s_barrier();
    MFMA_Q(a, b0, 4, 0)
    __builtin_amdgcn_s_barrier();
  }
#undef LDA
#undef LDB
#undef MFMA_Q

  // epilogue under the remapped wave->output assignment:
  // rows: m<4 -> wr*64 + m*16 ; m>=4 -> 128 + wr*64 + (m-4)*16
  // cols: n<2 -> wc*32 + n*16 ; n>=2 -> 128 + wc*32 + (n-2)*16
  int rq = (lane >> 4) * 4;
#pragma unroll
  for (int n = 0; n < 4; ++n) {
    int gc = bn * 256 + (n >= 2 ? 128 : 0) + wc32 + (n & 1) * 16 + lr;
    float bv = bias[gc];
#pragma unroll
    for (int m = 0; m < 8; ++m) {
      long long gr = (long long)bm * 256 + (m >= 4 ? 128 : 0) + wr64 + (m & 3) * 16 + rq;
#pragma unroll
      for (int v = 0; v < 4; ++v)
        Out[(gr + v) * N + gc] = acc[m][n][v] + bv;
    }
  }
}

// ---------------------------------------------------------------------------
extern "C" void kernel_launch(void* const* d_in, const int* in_sizes, int n_in,
                              void* d_out, int out_size, void* d_ws, size_t ws_size,
                              hipStream_t stream) {
  const float* x    = (const float*)d_in[0];
  const float* W    = (const float*)d_in[1];
  const float* bias = (const float*)d_in[2];
  const float* A    = (const float*)d_in[3];
  const float* B    = (const float*)d_in[4];

  int Din  = in_sizes[3] / RANK;                 // 4096
  int Dout = in_sizes[4] / RANK;                 // 4096
  long long M = (long long)in_sizes[0] / Din;    // 8192

  size_t xb_bytes = (size_t)M * Din * 2;
  size_t wb_bytes = (size_t)Dout * Din * 2;
  size_t bt_bytes = (size_t)Dout * RANK * 4;
  if (ws_size < xb_bytes + wb_bytes + bt_bytes) return;

  char* ws = (char*)d_ws;
  unsigned short* Xb = (unsigned short*)ws;
  unsigned short* Wb = (unsigned short*)(ws + xb_bytes);
  float* Bt          = (float*)(ws + xb_bytes + wb_bytes);

  transpose_B_k<<<dim3((Dout * RANK) / 256), dim3(256), 0, stream>>>(B, Bt, Dout);
  merge_W_k<<<dim3((Dout / 16) * (Din / 256)), dim3(256), 0, stream>>>(W, A, Bt, Wb, Din, Dout);
  long long n8 = M * Din / 8;
  cast_x_k<<<dim3((unsigned)(n8 / 256)), dim3(256), 0, stream>>>(x, Xb, n8);
  gemm256_bias_k<<<dim3((unsigned)((M / 256) * (Dout / 256))), dim3(512), 0, stream>>>(
      Xb, Wb, bias, (float*)d_out, (int)M, Dout, Din);
}

// Round 6
// 329.381 us; speedup vs baseline: 1.1908x; 1.0501x over previous
//
#include <hip/hip_runtime.h>
#include <hip/hip_bf16.h>
#include <stdint.h>

#define RANK 32
#define SCALE (1.0f / 32.0f)

typedef __bf16 bf16x8 __attribute__((ext_vector_type(8)));
typedef float f32x4 __attribute__((ext_vector_type(4)));

// ---------------------------------------------------------------------------
// async global->LDS, 16B per lane
// ---------------------------------------------------------------------------
__device__ __forceinline__ void gload16(const void* g, void* l) {
  __builtin_amdgcn_global_load_lds(
      (const __attribute__((address_space(1))) unsigned int*)g,
      (__attribute__((address_space(3))) unsigned int*)l, 16, 0, 0);
}

__device__ __forceinline__ unsigned short f2bf(float f) {
  __hip_bfloat16 h = __float2bfloat16(f);
  return *reinterpret_cast<unsigned short*>(&h);
}

// ---------------------------------------------------------------------------
// Bt[o][r] = B[r][o]
// ---------------------------------------------------------------------------
__global__ __launch_bounds__(256) void transpose_B_k(const float* __restrict__ B,
                                                     float* __restrict__ Bt,
                                                     int Dout) {
  int idx = blockIdx.x * 256 + threadIdx.x;
  int r = idx / Dout;
  int o = idx - r * Dout;
  Bt[(long long)o * RANK + r] = B[idx];
}

// ---------------------------------------------------------------------------
// W'b[o][i] = bf16( W[o][i] + SCALE * dot32(A[i][:], Bt[o][:]) )
// W is single-use: nontemporal load keeps it out of L3 (preserve Xb/Wb).
// ---------------------------------------------------------------------------
__global__ __launch_bounds__(256) void merge_W_k(const float* __restrict__ W,
                                                 const float* __restrict__ A,
                                                 const float* __restrict__ Bt,
                                                 unsigned short* __restrict__ Wb,
                                                 int Din, int Dout) {
  __shared__ float sB[16 * RANK];
  int nib = Din / 256;
  int ib = blockIdx.x % nib;
  int ob = blockIdx.x / nib;
  int i0 = ib * 256, o0 = ob * 16;
  int t = threadIdx.x;

  if (t < 128) {
    reinterpret_cast<float4*>(sB)[t] =
        reinterpret_cast<const float4*>(Bt + (long long)o0 * RANK)[t];
  }

  float a[RANK];
  const float4* Ap = reinterpret_cast<const float4*>(A + (long long)(i0 + t) * RANK);
#pragma unroll
  for (int c = 0; c < RANK / 4; ++c) {
    float4 v = Ap[c];
    a[c * 4 + 0] = v.x; a[c * 4 + 1] = v.y;
    a[c * 4 + 2] = v.z; a[c * 4 + 3] = v.w;
  }
  __syncthreads();

  for (int o = 0; o < 16; ++o) {
    float d = 0.f;
#pragma unroll
    for (int j = 0; j < RANK; ++j) d += a[j] * sB[o * RANK + j];
    long long off = (long long)(o0 + o) * Din + i0 + t;
    float w = __builtin_nontemporal_load(&W[off]);
    Wb[off] = f2bf(w + SCALE * d);
  }
}

// ---------------------------------------------------------------------------
// x fp32 -> bf16, 8 elems/thread. x is single-use: nontemporal loads
// (via native ext_vector float4 — HIP_vector_type is rejected by the builtin).
// ---------------------------------------------------------------------------
__global__ __launch_bounds__(256) void cast_x_k(const float* __restrict__ in,
                                                unsigned short* __restrict__ out,
                                                long long n8) {
  long long i = (long long)blockIdx.x * 256 + threadIdx.x;
  if (i >= n8) return;
  const f32x4* in4 = reinterpret_cast<const f32x4*>(in) + i * 2;
  f32x4 v0 = __builtin_nontemporal_load(in4);
  f32x4 v1 = __builtin_nontemporal_load(in4 + 1);
  union { unsigned short u[8]; uint4 q; } p;
  p.u[0] = f2bf(v0.x); p.u[1] = f2bf(v0.y); p.u[2] = f2bf(v0.z); p.u[3] = f2bf(v0.w);
  p.u[4] = f2bf(v1.x); p.u[5] = f2bf(v1.y); p.u[6] = f2bf(v1.z); p.u[7] = f2bf(v1.w);
  reinterpret_cast<uint4*>(out)[i] = p.q;
}

// ---------------------------------------------------------------------------
// Faithful m201 geometry: 256x256 / BK=64 / 8 waves (2Mx4N) / 2 K-tiles per
// iteration / 8 phases / 1 half-tile (2 gloads) staged per phase /
// vmcnt(6) = 3 half-tiles in flight, at phases 4 and 8 only.
// (Schedule identical to R4 — verified passing. R5 changes: nt Out stores,
// nt single-use prep loads, bm-fastest XCD chunk order.)
// ---------------------------------------------------------------------------
__device__ __forceinline__ void stage2(const unsigned short* g, int K, int koff,
                                       int row0, unsigned short* ldsreg,
                                       int t, int wid) {
  int r = t >> 3;                    // 0..63
  int cg = (t & 7) ^ (r & 7);        // inverse-swizzled global 16B chunk
  gload16(g + (long long)(row0 + r) * K + koff + cg * 8,
          ldsreg + row0 * 64 + wid * 512);
  gload16(g + (long long)(row0 + 64 + r) * K + koff + cg * 8,
          ldsreg + (row0 + 64) * 64 + wid * 512);
}

__device__ __forceinline__ int swz_off(int rowl, int k) {
  return rowl * 64 + ((((k) >> 3) ^ (rowl & 7)) << 3);
}

__global__ __launch_bounds__(512, 2) void gemm256_bias_k(
    const unsigned short* __restrict__ Xb,   // [M][K] bf16
    const unsigned short* __restrict__ Wb,   // [N][K] bf16
    const float* __restrict__ bias,          // [N]
    float* __restrict__ Out,                 // [M][N] fp32
    int M, int N, int K) {
  __shared__ unsigned short As[2][256 * 64];
  __shared__ unsigned short Bs[2][256 * 64];

  int nbn = N / 256;
  int cpx = gridDim.x >> 3;
  int bid = blockIdx.x;
  int xcd = bid & 7, local = bid >> 3;
  int bm, bn;
  int mrows = cpx / nbn;
  if (mrows * nbn == cpx) {
    // bm-fastest within XCD chunk: B-panel (2MB) reuse distance 1 -> L2-hot
    bn = local / mrows;
    bm = xcd * mrows + (local - bn * mrows);
  } else {
    int swz = xcd * cpx + local;
    bm = swz / nbn; bn = swz % nbn;
  }

  int t = threadIdx.x;
  int wid = t >> 6, lane = t & 63;
  int wr = wid >> 2, wc = wid & 3;             // 2x4 wave grid
  int lr = lane & 15, kq = (lane >> 4) * 8;
  int wr64 = wr * 64, wc32 = wc * 32;

  const unsigned short* ga = Xb + (long long)bm * 256 * K;
  const unsigned short* gb = Wb + (long long)bn * 256 * K;

  f32x4 acc[8][4] = {};
  bf16x8 a[4][2], b0[2][2], b1[2][2];

  const int NT = K / 64;        // 64
  const int iters = NT / 2;     // 32

#define LDA(BUF, ROWBASE, KS) \
  (*(const bf16x8*)&As[BUF][swz_off((ROWBASE) + lr, (KS) * 32 + kq)])
#define LDB(BUF, ROWBASE, KS) \
  (*(const bf16x8*)&Bs[BUF][swz_off((ROWBASE) + lr, (KS) * 32 + kq)])

#define MFMA_Q(ACLUST, BCLUST, MOFF, NOFF)                                   \
  __builtin_amdgcn_s_setprio(1);                                             \
  _Pragma("unroll")                                                          \
  for (int m = 0; m < 4; ++m)                                                \
    _Pragma("unroll")                                                        \
    for (int n = 0; n < 2; ++n)                                              \
      _Pragma("unroll")                                                      \
      for (int ks = 0; ks < 2; ++ks)                                         \
        acc[(MOFF) + m][(NOFF) + n] = __builtin_amdgcn_mfma_f32_16x16x32_bf16(\
            ACLUST[m][ks], BCLUST[n][ks], acc[(MOFF) + m][(NOFF) + n], 0, 0, 0); \
  __builtin_amdgcn_s_setprio(0);

  // ---- prologue: tile0 (buf0) full + tile1 (buf1) Ha1,Hb1,Hb2; vmcnt(6)
  stage2(ga, K, 0, 0, &As[0][0], t, wid);     // Ha1(0)
  stage2(gb, K, 0, 0, &Bs[0][0], t, wid);     // Hb1(0)
  stage2(gb, K, 0, 128, &Bs[0][0], t, wid);   // Hb2(0)
  stage2(ga, K, 0, 128, &As[0][0], t, wid);   // Ha2(0)
  stage2(ga, K, 64, 0, &As[1][0], t, wid);    // Ha1(1)
  stage2(gb, K, 64, 0, &Bs[1][0], t, wid);    // Hb1(1)
  stage2(gb, K, 64, 128, &Bs[1][0], t, wid);  // Hb2(1)
  asm volatile("s_waitcnt vmcnt(6)" ::: "memory");
  __builtin_amdgcn_s_barrier();

  for (int j = 0; j < iters; ++j) {
    const bool more = (j + 1 < iters);
    int koY = (2 * j + 1) * 64, koX2 = koY + 64, koY2 = koX2 + 64;

    // ---------- P1 (tile X=2j, Q1): read a_lo,b_lo; stage Ha2(Y)->buf1
#pragma unroll
    for (int m = 0; m < 4; ++m) {
      a[m][0] = LDA(0, wr64 + m * 16, 0); a[m][1] = LDA(0, wr64 + m * 16, 1);
    }
#pragma unroll
    for (int n = 0; n < 2; ++n) {
      b0[n][0] = LDB(0, wc32 + n * 16, 0); b0[n][1] = LDB(0, wc32 + n * 16, 1);
    }
    stage2(ga, K, koY, 128, &As[1][0], t, wid);
    __builtin_amdgcn_s_barrier();
    MFMA_Q(a, b0, 0, 0)
    __builtin_amdgcn_s_barrier();

    // ---------- P2 (Q2): read b_hi; stage Ha1(X')->buf0
#pragma unroll
    for (int n = 0; n < 2; ++n) {
      b1[n][0] = LDB(0, 128 + wc32 + n * 16, 0); b1[n][1] = LDB(0, 128 + wc32 + n * 16, 1);
    }
    if (more) stage2(ga, K, koX2, 0, &As[0][0], t, wid);
    __builtin_amdgcn_s_barrier();
    MFMA_Q(a, b1, 0, 2)
    __builtin_amdgcn_s_barrier();

    // ---------- P3 (Q3): read a_hi; stage Hb1(X')->buf0
#pragma unroll
    for (int m = 0; m < 4; ++m) {
      a[m][0] = LDA(0, 128 + wr64 + m * 16, 0); a[m][1] = LDA(0, 128 + wr64 + m * 16, 1);
    }
    if (more) stage2(gb, K, koX2, 0, &Bs[0][0], t, wid);
    __builtin_amdgcn_s_barrier();
    MFMA_Q(a, b1, 4, 2)
    __builtin_amdgcn_s_barrier();

    // ---------- P4 (Q4): stage Hb2(X')->buf0; counted vmcnt
    if (more) {
      stage2(gb, K, koX2, 128, &Bs[0][0], t, wid);
      asm volatile("s_waitcnt vmcnt(6)" ::: "memory");
    } else {
      asm volatile("s_waitcnt vmcnt(0)" ::: "memory");
    }
    __builtin_amdgcn_s_barrier();
    MFMA_Q(a, b0, 4, 0)
    __builtin_amdgcn_s_barrier();

    // ---------- P5 (tile Y=2j+1, Q1): stage Ha2(X')->buf0
#pragma unroll
    for (int m = 0; m < 4; ++m) {
      a[m][0] = LDA(1, wr64 + m * 16, 0); a[m][1] = LDA(1, wr64 + m * 16, 1);
    }
#pragma unroll
    for (int n = 0; n < 2; ++n) {
      b0[n][0] = LDB(1, wc32 + n * 16, 0); b0[n][1] = LDB(1, wc32 + n * 16, 1);
    }
    if (more) stage2(ga, K, koX2, 128, &As[0][0], t, wid);
    __builtin_amdgcn_s_barrier();
    MFMA_Q(a, b0, 0, 0)
    __builtin_amdgcn_s_barrier();

    // ---------- P6 (Q2): stage Ha1(Y')->buf1
#pragma unroll
    for (int n = 0; n < 2; ++n) {
      b1[n][0] = LDB(1, 128 + wc32 + n * 16, 0); b1[n][1] = LDB(1, 128 + wc32 + n * 16, 1);
    }
    if (more) stage2(ga, K, koY2, 0, &As[1][0], t, wid);
    __builtin_amdgcn_s_barrier();
    MFMA_Q(a, b1, 0, 2)
    __builtin_amdgcn_s_barrier();

    // ---------- P7 (Q3): stage Hb1(Y')->buf1
#pragma unroll
    for (int m = 0; m < 4; ++m) {
      a[m][0] = LDA(1, 128 + wr64 + m * 16, 0); a[m][1] = LDA(1, 128 + wr64 + m * 16, 1);
    }
    if (more) stage2(gb, K, koY2, 0, &Bs[1][0], t, wid);
    __builtin_amdgcn_s_barrier();
    MFMA_Q(a, b1, 4, 2)
    __builtin_amdgcn_s_barrier();

    // ---------- P8 (Q4): stage Hb2(Y')->buf1; counted vmcnt
    if (more) {
      stage2(gb, K, koY2, 128, &Bs[1][0], t, wid);
      asm volatile("s_waitcnt vmcnt(6)" ::: "memory");
    }
    __builtin_amdgcn_s_barrier();
    MFMA_Q(a, b0, 4, 0)
    __builtin_amdgcn_s_barrier();
  }
#undef LDA
#undef LDB
#undef MFMA_Q

  // epilogue (nontemporal stores: Out is write-once, keep it out of L3):
  // rows: m<4 -> wr*64 + m*16 ; m>=4 -> 128 + wr*64 + (m-4)*16
  // cols: n<2 -> wc*32 + n*16 ; n>=2 -> 128 + wc*32 + (n-2)*16
  int rq = (lane >> 4) * 4;
#pragma unroll
  for (int n = 0; n < 4; ++n) {
    int gc = bn * 256 + (n >= 2 ? 128 : 0) + wc32 + (n & 1) * 16 + lr;
    float bv = bias[gc];
#pragma unroll
    for (int m = 0; m < 8; ++m) {
      long long gr = (long long)bm * 256 + (m >= 4 ? 128 : 0) + wr64 + (m & 3) * 16 + rq;
#pragma unroll
      for (int v = 0; v < 4; ++v)
        __builtin_nontemporal_store(acc[m][n][v] + bv, &Out[(gr + v) * N + gc]);
    }
  }
}

// ---------------------------------------------------------------------------
extern "C" void kernel_launch(void* const* d_in, const int* in_sizes, int n_in,
                              void* d_out, int out_size, void* d_ws, size_t ws_size,
                              hipStream_t stream) {
  const float* x    = (const float*)d_in[0];
  const float* W    = (const float*)d_in[1];
  const float* bias = (const float*)d_in[2];
  const float* A    = (const float*)d_in[3];
  const float* B    = (const float*)d_in[4];

  int Din  = in_sizes[3] / RANK;                 // 4096
  int Dout = in_sizes[4] / RANK;                 // 4096
  long long M = (long long)in_sizes[0] / Din;    // 8192

  size_t xb_bytes = (size_t)M * Din * 2;
  size_t wb_bytes = (size_t)Dout * Din * 2;
  size_t bt_bytes = (size_t)Dout * RANK * 4;
  if (ws_size < xb_bytes + wb_bytes + bt_bytes) return;

  char* ws = (char*)d_ws;
  unsigned short* Xb = (unsigned short*)ws;
  unsigned short* Wb = (unsigned short*)(ws + xb_bytes);
  float* Bt          = (float*)(ws + xb_bytes + wb_bytes);

  transpose_B_k<<<dim3((Dout * RANK) / 256), dim3(256), 0, stream>>>(B, Bt, Dout);
  merge_W_k<<<dim3((Dout / 16) * (Din / 256)), dim3(256), 0, stream>>>(W, A, Bt, Wb, Din, Dout);
  long long n8 = M * Din / 8;
  cast_x_k<<<dim3((unsigned)(n8 / 256)), dim3(256), 0, stream>>>(x, Xb, n8);
  gemm256_bias_k<<<dim3((unsigned)((M / 256) * (Dout / 256))), dim3(512), 0, stream>>>(
      Xb, Wb, bias, (float*)d_out, (int)M, Dout, Din);
}